// Round 1
// baseline (606.967 us; speedup 1.0000x reference)
//
#include <hip/hip_runtime.h>
#include <stdint.h>

#define B_ 16
#define S1_ 2048
#define S2_ 2048
#define H_ 512

typedef short short8 __attribute__((ext_vector_type(8)));
typedef float f32x4 __attribute__((ext_vector_type(4)));

__device__ __forceinline__ unsigned short f2bf(float f) {
  unsigned u = __builtin_bit_cast(unsigned, f);
  u += 0x7fffu + ((u >> 16) & 1u);          // round-to-nearest-even
  return (unsigned short)(u >> 16);
}

__device__ __forceinline__ void gload_lds16(const void* g, void* l) {
  __builtin_amdgcn_global_load_lds((const __attribute__((address_space(1))) void*)g,
                                   (__attribute__((address_space(3))) void*)l,
                                   16, 0, 0);
}

// ---------------- prep: row l2-normalize fp32 -> bf16 ----------------
__global__ __launch_bounds__(256) void k_rownorm(const float* __restrict__ x,
                                                 unsigned short* __restrict__ y) {
  int row = blockIdx.x * 4 + (threadIdx.x >> 6);
  int l = threadIdx.x & 63;
  const f32x4* xr = (const f32x4*)(x + (size_t)row * H_) + l * 2;
  f32x4 a = xr[0], b = xr[1];
  float s = a[0]*a[0] + a[1]*a[1] + a[2]*a[2] + a[3]*a[3]
          + b[0]*b[0] + b[1]*b[1] + b[2]*b[2] + b[3]*b[3];
#pragma unroll
  for (int m = 1; m < 64; m <<= 1) s += __shfl_xor(s, m);
  float sc = 1.0f / fmaxf(sqrtf(s), 1e-12f);
  short8 o;
#pragma unroll
  for (int i = 0; i < 4; ++i) { o[i] = (short)f2bf(a[i] * sc); o[4 + i] = (short)f2bf(b[i] * sc); }
  *(short8*)(y + (size_t)row * H_ + l * 8) = o;
}

// ---------------- prep: transpose+cast weights W[R][C] -> WT[C][R] bf16 ----------------
__global__ __launch_bounds__(256) void k_tw(const float* __restrict__ Wm,
                                            unsigned short* __restrict__ WT,
                                            int lgR, int C) {
  int i = blockIdx.x * 256 + threadIdx.x;     // over C*R outputs
  int R = 1 << lgR;
  int n = i >> lgR, k = i & (R - 1);
  WT[i] = f2bf(Wm[(size_t)k * C + n]);
}

// ---------------- prep: vt[b][h][s] bf16 = transpose(text2[b][s][h]) ----------------
__global__ __launch_bounds__(256) void k_tvt(const float* __restrict__ t2,
                                             unsigned short* __restrict__ vt) {
  __shared__ unsigned short tile[64][72];
  int h0 = blockIdx.x * 64, s0 = blockIdx.y * 64, b = blockIdx.z;
  int t = threadIdx.x;
#pragma unroll
  for (int p = 0; p < 4; ++p) {
    int si = p * 16 + (t >> 4);
    int cj = (t & 15) * 4;
    f32x4 v = *(const f32x4*)(t2 + ((size_t)(b * S2_ + s0 + si)) * H_ + h0 + cj);
    tile[si][cj]     = f2bf(v[0]);
    tile[si][cj + 1] = f2bf(v[1]);
    tile[si][cj + 2] = f2bf(v[2]);
    tile[si][cj + 3] = f2bf(v[3]);
  }
  __syncthreads();
#pragma unroll
  for (int p = 0; p < 2; ++p) {
    int ho = p * 32 + (t >> 3);
    int sx = (t & 7) * 8;
    short8 o;
#pragma unroll
    for (int x = 0; x < 8; ++x) o[x] = (short)tile[sx + x][ho];
    *(short8*)(vt + ((size_t)(b * H_ + h0 + ho)) * S2_ + s0 + sx) = o;
  }
}

// ---------------- fused cosine-sim flash attention + LN1 + residual ----------------
// Block: 256 thr (4 waves). Wave w owns q-rows [q0+16w, q0+16w+16), full D=512.
// Fixed-shift softmax: exp(s-1) (cosine sims bounded by ~1) -> no online max/rescale.
__global__ __launch_bounds__(256, 1) void k_attn(
    const unsigned short* __restrict__ qn, const unsigned short* __restrict__ kn,
    const unsigned short* __restrict__ vt, const int* __restrict__ mask2,
    const float* __restrict__ text1, const float* __restrict__ g1,
    const float* __restrict__ bb1, unsigned short* __restrict__ nattn,
    float* __restrict__ resid) {
  __shared__ unsigned short uK[20480];     // union: K tile [32][512] (32KB) / VT tile [512][40] (40KB)
  __shared__ unsigned short uP[4][512];    // per-wave P tile [16][32] bf16

  const int b = blockIdx.y;
  const int q0 = blockIdx.x * 64;
  const int w = threadIdx.x >> 6, l = threadIdx.x & 63;
  const int lr = l & 15, lk = l >> 4;

  // Q fragments in registers: A[m=lr][k], one short8 per kstep
  short8 qf[16];
  const unsigned short* qbase = qn + (size_t)(b * S1_ + q0 + w * 16 + lr) * H_;
#pragma unroll
  for (int kk = 0; kk < 16; ++kk) qf[kk] = *(const short8*)(qbase + kk * 32 + lk * 8);

  f32x4 acc[32];
#pragma unroll
  for (int i = 0; i < 32; ++i) acc[i] = (f32x4){0.f, 0.f, 0.f, 0.f};
  float lsum[4] = {0.f, 0.f, 0.f, 0.f};

#pragma unroll 1
  for (int t = 0; t < S2_ / 32; ++t) {
    const int kv0 = t * 32;
    // ---- stage K tile (32 rows x 512) via global_load_lds, source-side XOR swizzle
#pragma unroll
    for (int c = 0; c < 8; ++c) {
      int r = c * 4 + w;  // one row (1024B) per wave per call
      const char* src = (const char*)(kn + (size_t)(b * S2_ + kv0 + r) * H_)
                      + ((l * 16) ^ ((r & 7) << 4));
      gload_lds16(src, (char*)uK + c * 4096 + w * 1024);
    }
    asm volatile("s_waitcnt vmcnt(0)" ::: "memory");
    __syncthreads();

    // ---- QK^T + exp(s-1)*mask -> P (LDS), lsum
#pragma unroll
    for (int nf = 0; nf < 2; ++nf) {
      f32x4 c = {0.f, 0.f, 0.f, 0.f};
      int krow = nf * 16 + lr;
      const unsigned short* kb = uK + krow * 512;
      int sw = (krow & 7) << 3;  // swizzle in shorts
#pragma unroll
      for (int kk = 0; kk < 16; ++kk) {
        short8 bf = *(const short8*)(kb + ((kk * 32 + lk * 8) ^ sw));
        c = __builtin_amdgcn_mfma_f32_16x16x32_bf16(qf[kk], bf, c, 0, 0, 0);
      }
      float mv = (mask2[b * S2_ + kv0 + nf * 16 + lr] != 0) ? 1.0f : 0.0f;
#pragma unroll
      for (int r = 0; r < 4; ++r) {
        float p = __expf(c[r] - 1.0f) * mv;
        lsum[r] += p;
        uP[w][(lk * 4 + r) * 32 + nf * 16 + lr] = f2bf(p);
      }
    }
    __syncthreads();   // all waves done reading K

    // ---- stage VT tile [512][40-pad] manually (overwrites K union)
#pragma unroll
    for (int it = 0; it < 8; ++it) {
      int n = it * 64 + (threadIdx.x >> 2);
      int q = threadIdx.x & 3;
      short8 v = *(const short8*)(vt + (size_t)(b * H_ + n) * S2_ + kv0 + q * 8);
      *(short8*)(uK + n * 40 + q * 8) = v;
    }
    __syncthreads();

    // ---- PV: O[16][512] += P[16][32] @ V[32][512]
    short8 pa = *(const short8*)(uP[w] + lr * 32 + lk * 8);
#pragma unroll
    for (int nf2 = 0; nf2 < 32; ++nf2) {
      short8 bf = *(const short8*)(uK + (nf2 * 16 + lr) * 40 + lk * 8);
      acc[nf2] = __builtin_amdgcn_mfma_f32_16x16x32_bf16(pa, bf, acc[nf2], 0, 0, 0);
    }
    __syncthreads();   // before next K staging overwrites VT
  }

  // ---- 1/l per row (rows lk*4+r live in 16-lane groups)
  float rl[4];
#pragma unroll
  for (int r = 0; r < 4; ++r) {
    float s = lsum[r];
    s += __shfl_xor(s, 1); s += __shfl_xor(s, 2); s += __shfl_xor(s, 4); s += __shfl_xor(s, 8);
    rl[r] = 1.0f / s;
  }

  // ---- scale + LN1 stats
  float sum[4] = {0.f, 0.f, 0.f, 0.f}, sq[4] = {0.f, 0.f, 0.f, 0.f};
#pragma unroll
  for (int nf = 0; nf < 32; ++nf)
#pragma unroll
    for (int r = 0; r < 4; ++r) {
      float x = acc[nf][r] * rl[r];
      acc[nf][r] = x;
      sum[r] += x; sq[r] += x * x;
    }
  float mean_[4], rstd_[4];
#pragma unroll
  for (int r = 0; r < 4; ++r) {
    float s = sum[r], q = sq[r];
    s += __shfl_xor(s, 1); s += __shfl_xor(s, 2); s += __shfl_xor(s, 4); s += __shfl_xor(s, 8);
    q += __shfl_xor(q, 1); q += __shfl_xor(q, 2); q += __shfl_xor(q, 4); q += __shfl_xor(q, 8);
    float mean = s * (1.f / 512.f);
    float var = q * (1.f / 512.f) - mean * mean;
    mean_[r] = mean;
    rstd_[r] = rsqrtf(var + 1e-6f);
  }

  // ---- write norm_attn (bf16) and resid = norm_attn + text1 (fp32)
  size_t rowbase = (size_t)(b * S1_ + q0 + w * 16);
#pragma unroll
  for (int nf = 0; nf < 32; ++nf) {
    int col = nf * 16 + lr;
    float gg = g1[col], bbv = bb1[col];
#pragma unroll
    for (int r = 0; r < 4; ++r) {
      size_t idx = (rowbase + lk * 4 + r) * H_ + col;
      float y = (acc[nf][r] - mean_[r]) * rstd_[r] * gg + bbv;
      nattn[idx] = f2bf(y);
      resid[idx] = y + text1[idx];
    }
  }
}

// ---------------- bf16 GEMM: C[M][N] = act(A[M][K] @ BT[N][K]^T + bias) ----------------
template <int RELU, int OUTBF16>
__global__ __launch_bounds__(256, 2) void k_gemm(const unsigned short* __restrict__ A,
                                                 const unsigned short* __restrict__ BT,
                                                 const float* __restrict__ bias,
                                                 void* __restrict__ out,
                                                 int M, int N, int K) {
  __shared__ unsigned short lA[128 * 64];
  __shared__ unsigned short lB[128 * 64];
  int w = threadIdx.x >> 6, l = threadIdx.x & 63;
  int lr = l & 15, lk = l >> 4;
  int m0 = blockIdx.y * 128, n0 = blockIdx.x * 128;
  int wm = (w >> 1) * 64, wn = (w & 1) * 64;
  f32x4 acc[4][4];
#pragma unroll
  for (int i = 0; i < 4; ++i)
#pragma unroll
    for (int j = 0; j < 4; ++j) acc[i][j] = (f32x4){0.f, 0.f, 0.f, 0.f};

#pragma unroll 1
  for (int kt = 0; kt < K; kt += 64) {
#pragma unroll
    for (int j = 0; j < 4; ++j) {
      int d = (j * 4 + w) * 1024 + l * 16;
      int row = d >> 7;
      int off = (d & 127) ^ ((row & 7) << 4);
      gload_lds16((const char*)A + (((size_t)(m0 + row) * K + kt) << 1) + off,
                  (char*)lA + (j * 4 + w) * 1024);
      gload_lds16((const char*)BT + (((size_t)(n0 + row) * K + kt) << 1) + off,
                  (char*)lB + (j * 4 + w) * 1024);
    }
    asm volatile("s_waitcnt vmcnt(0)" ::: "memory");
    __syncthreads();
#pragma unroll
    for (int s = 0; s < 2; ++s) {
      short8 af[4], bf[4];
#pragma unroll
      for (int mi = 0; mi < 4; ++mi) {
        int row = wm + mi * 16 + lr;
        af[mi] = *(const short8*)(lA + row * 64 + ((s * 32 + lk * 8) ^ ((row & 7) << 3)));
      }
#pragma unroll
      for (int ni = 0; ni < 4; ++ni) {
        int row = wn + ni * 16 + lr;
        bf[ni] = *(const short8*)(lB + row * 64 + ((s * 32 + lk * 8) ^ ((row & 7) << 3)));
      }
#pragma unroll
      for (int mi = 0; mi < 4; ++mi)
#pragma unroll
        for (int ni = 0; ni < 4; ++ni)
          acc[mi][ni] = __builtin_amdgcn_mfma_f32_16x16x32_bf16(af[mi], bf[ni], acc[mi][ni], 0, 0, 0);
    }
    __syncthreads();
  }

#pragma unroll
  for (int mi = 0; mi < 4; ++mi)
#pragma unroll
    for (int ni = 0; ni < 4; ++ni) {
      int gn = n0 + wn + ni * 16 + lr;
      float bs = bias[gn];
#pragma unroll
      for (int r = 0; r < 4; ++r) {
        int gm = m0 + wm + mi * 16 + lk * 4 + r;
        float v = acc[mi][ni][r] + bs;
        if (RELU) v = fmaxf(v, 0.f);
        if (OUTBF16) ((unsigned short*)out)[(size_t)gm * N + gn] = f2bf(v);
        else         ((float*)out)[(size_t)gm * N + gn] = v;
      }
    }
}

// ---------------- LN2(ff) + resid -> out ----------------
__global__ __launch_bounds__(256) void k_ln2(const float* __restrict__ ff,
                                             const float* __restrict__ resid,
                                             const float* __restrict__ g2,
                                             const float* __restrict__ bb2,
                                             float* __restrict__ out) {
  int row = blockIdx.x * 4 + (threadIdx.x >> 6);
  int l = threadIdx.x & 63;
  size_t base = (size_t)row * H_ + l * 8;
  f32x4 x0 = *(const f32x4*)(ff + base);
  f32x4 x1 = *(const f32x4*)(ff + base + 4);
  float s = x0[0] + x0[1] + x0[2] + x0[3] + x1[0] + x1[1] + x1[2] + x1[3];
  float q = x0[0]*x0[0] + x0[1]*x0[1] + x0[2]*x0[2] + x0[3]*x0[3]
          + x1[0]*x1[0] + x1[1]*x1[1] + x1[2]*x1[2] + x1[3]*x1[3];
#pragma unroll
  for (int m = 1; m < 64; m <<= 1) { s += __shfl_xor(s, m); q += __shfl_xor(q, m); }
  float mean = s * (1.f / 512.f);
  float var = q * (1.f / 512.f) - mean * mean;
  float rstd = rsqrtf(var + 1e-6f);
  f32x4 g0 = *(const f32x4*)(g2 + l * 8), g1v = *(const f32x4*)(g2 + l * 8 + 4);
  f32x4 b0 = *(const f32x4*)(bb2 + l * 8), b1v = *(const f32x4*)(bb2 + l * 8 + 4);
  f32x4 r0 = *(const f32x4*)(resid + base), r1 = *(const f32x4*)(resid + base + 4);
  f32x4 o0, o1;
#pragma unroll
  for (int i = 0; i < 4; ++i) {
    o0[i] = (x0[i] - mean) * rstd * g0[i] + b0[i] + r0[i];
    o1[i] = (x1[i] - mean) * rstd * g1v[i] + b1v[i] + r1[i];
  }
  *(f32x4*)(out + base) = o0;
  *(f32x4*)(out + base + 4) = o1;
}

extern "C" void kernel_launch(void* const* d_in, const int* in_sizes, int n_in,
                              void* d_out, int out_size, void* d_ws, size_t ws_size,
                              hipStream_t stream) {
  const float* text1 = (const float*)d_in[0];
  const float* text2 = (const float*)d_in[1];
  // d_in[2] = text1_mask (unused by reference output)
  const int* mask2 = (const int*)d_in[3];
  const float* W1 = (const float*)d_in[4];
  const float* b1 = (const float*)d_in[5];
  const float* W2 = (const float*)d_in[6];
  const float* b2 = (const float*)d_in[7];
  const float* g1 = (const float*)d_in[8];
  const float* bb1 = (const float*)d_in[9];
  const float* g2 = (const float*)d_in[10];
  const float* bb2 = (const float*)d_in[11];

  char* ws = (char*)d_ws;
  unsigned short* qn    = (unsigned short*)(ws);                 // 32 MiB
  unsigned short* kn    = (unsigned short*)(ws + (33554432u));   // 32 MiB
  unsigned short* vt    = (unsigned short*)(ws + (67108864u));   // 32 MiB
  unsigned short* nattn = (unsigned short*)(ws + (100663296u));  // 32 MiB
  float*          resid = (float*)(ws + (134217728u));           // 64 MiB
  unsigned short* W1T   = (unsigned short*)(ws + (201326592u));  // 1 MiB
  unsigned short* W2T   = (unsigned short*)(ws + (202375168u));  // 1 MiB
  unsigned short* h     = (unsigned short*)(ws);                 // aliases qn+kn (dead after attn)
  float*          ff    = (float*)(ws + (67108864u));            // aliases vt+nattn (dead after FF1)
  float* outp = (float*)d_out;

  k_rownorm<<<dim3(B_ * S1_ / 4), 256, 0, stream>>>(text1, qn);
  k_rownorm<<<dim3(B_ * S2_ / 4), 256, 0, stream>>>(text2, kn);
  k_tw<<<dim3(512 * 1024 / 256), 256, 0, stream>>>(W1, W1T, 9, 1024);
  k_tw<<<dim3(512 * 1024 / 256), 256, 0, stream>>>(W2, W2T, 10, 512);
  k_tvt<<<dim3(H_ / 64, S2_ / 64, B_), 256, 0, stream>>>(text2, vt);
  k_attn<<<dim3(S1_ / 64, B_), 256, 0, stream>>>(qn, kn, vt, mask2, text1, g1, bb1, nattn, resid);
  k_gemm<1, 1><<<dim3(1024 / 128, 32768 / 128), 256, 0, stream>>>(nattn, W1T, b1, h, 32768, 1024, 512);
  k_gemm<0, 0><<<dim3(512 / 128, 32768 / 128), 256, 0, stream>>>(h, W2T, b2, ff, 32768, 512, 1024);
  k_ln2<<<dim3(32768 / 4), 256, 0, stream>>>(ff, resid, g2, bb2, outp);
}

// Round 2
// 432.803 us; speedup vs baseline: 1.4024x; 1.4024x over previous
//
#include <hip/hip_runtime.h>
#include <stdint.h>

#define B_ 16
#define S1_ 2048
#define S2_ 2048
#define H_ 512

typedef short short8 __attribute__((ext_vector_type(8)));
typedef float f32x4 __attribute__((ext_vector_type(4)));

__device__ __forceinline__ unsigned short f2bf(float f) {
  unsigned u = __builtin_bit_cast(unsigned, f);
  u += 0x7fffu + ((u >> 16) & 1u);          // round-to-nearest-even
  return (unsigned short)(u >> 16);
}
__device__ __forceinline__ float bf2f(unsigned short us) {
  return __builtin_bit_cast(float, (unsigned)us << 16);
}

__device__ __forceinline__ void gload_lds16(const void* g, void* l) {
  __builtin_amdgcn_global_load_lds((const __attribute__((address_space(1))) void*)g,
                                   (__attribute__((address_space(3))) void*)l,
                                   16, 0, 0);
}

// ---------------- prep: row l2-normalize fp32 -> bf16 ----------------
__global__ __launch_bounds__(256) void k_rownorm(const float* __restrict__ x,
                                                 unsigned short* __restrict__ y) {
  int row = blockIdx.x * 4 + (threadIdx.x >> 6);
  int l = threadIdx.x & 63;
  const f32x4* xr = (const f32x4*)(x + (size_t)row * H_) + l * 2;
  f32x4 a = xr[0], b = xr[1];
  float s = a[0]*a[0] + a[1]*a[1] + a[2]*a[2] + a[3]*a[3]
          + b[0]*b[0] + b[1]*b[1] + b[2]*b[2] + b[3]*b[3];
#pragma unroll
  for (int m = 1; m < 64; m <<= 1) s += __shfl_xor(s, m);
  float sc = 1.0f / fmaxf(sqrtf(s), 1e-12f);
  short8 o;
#pragma unroll
  for (int i = 0; i < 4; ++i) { o[i] = (short)f2bf(a[i] * sc); o[4 + i] = (short)f2bf(b[i] * sc); }
  *(short8*)(y + (size_t)row * H_ + l * 8) = o;
}

// ---------------- prep: transpose+cast weights W[R][C] -> WT[C][R] bf16 ----------------
__global__ __launch_bounds__(256) void k_tw(const float* __restrict__ Wm,
                                            unsigned short* __restrict__ WT,
                                            int lgR, int C) {
  int i = blockIdx.x * 256 + threadIdx.x;     // over C*R outputs
  int R = 1 << lgR;
  int n = i >> lgR, k = i & (R - 1);
  WT[i] = f2bf(Wm[(size_t)k * C + n]);
}

// ---------------- prep: vt[b][h][s] bf16 = transpose(text2[b][s][h]) ----------------
__global__ __launch_bounds__(256) void k_tvt(const float* __restrict__ t2,
                                             unsigned short* __restrict__ vt) {
  __shared__ unsigned short tile[64][72];
  int h0 = blockIdx.x * 64, s0 = blockIdx.y * 64, b = blockIdx.z;
  int t = threadIdx.x;
#pragma unroll
  for (int p = 0; p < 4; ++p) {
    int si = p * 16 + (t >> 4);
    int cj = (t & 15) * 4;
    f32x4 v = *(const f32x4*)(t2 + ((size_t)(b * S2_ + s0 + si)) * H_ + h0 + cj);
    tile[si][cj]     = f2bf(v[0]);
    tile[si][cj + 1] = f2bf(v[1]);
    tile[si][cj + 2] = f2bf(v[2]);
    tile[si][cj + 3] = f2bf(v[3]);
  }
  __syncthreads();
#pragma unroll
  for (int p = 0; p < 2; ++p) {
    int ho = p * 32 + (t >> 3);
    int sx = (t & 7) * 8;
    short8 o;
#pragma unroll
    for (int x = 0; x < 8; ++x) o[x] = (short)tile[sx + x][ho];
    *(short8*)(vt + ((size_t)(b * H_ + h0 + ho)) * S2_ + s0 + sx) = o;
  }
}

// ---------------- unified bf16 MFMA GEMM, batched via blockIdx.z ----------------
// C[M][N] = A[M][K] @ BT[N][K]^T, 128x128 tile, BK=64, 4 waves.
// MODE 0: FF1  -> relu(acc+bias), bf16 out
// MODE 1: FF2  -> acc+bias, f32 out
// MODE 2: attn pass1 -> p=exp(acc-1)*mask[n], bf16 out, atomicAdd row-sums into lbuf
// MODE 3: attn pass2 -> acc * (1/lbuf[row]), bf16 out
template <int MODE>
__global__ __launch_bounds__(256, 2) void k_gemm(
    const unsigned short* __restrict__ A, const unsigned short* __restrict__ BT,
    const float* __restrict__ bias, const int* __restrict__ mask,
    float* __restrict__ lbuf, void* __restrict__ out,
    int M, int N, int K, long sA, long sB, long sOut) {
  __shared__ unsigned short lA[128 * 64];
  __shared__ unsigned short lB[128 * 64];
  const int z = blockIdx.z;
  const unsigned short* Ab = A + (size_t)z * sA;
  const unsigned short* BTb = BT + (size_t)z * sB;
  int w = threadIdx.x >> 6, l = threadIdx.x & 63;
  int lr = l & 15, lk = l >> 4;
  int m0 = blockIdx.y * 128, n0 = blockIdx.x * 128;
  int wm = (w >> 1) * 64, wn = (w & 1) * 64;
  f32x4 acc[4][4];
#pragma unroll
  for (int i = 0; i < 4; ++i)
#pragma unroll
    for (int j = 0; j < 4; ++j) acc[i][j] = (f32x4){0.f, 0.f, 0.f, 0.f};

#pragma unroll 1
  for (int kt = 0; kt < K; kt += 64) {
#pragma unroll
    for (int j = 0; j < 4; ++j) {
      int d = (j * 4 + w) * 1024 + l * 16;
      int row = d >> 7;
      int off = (d & 127) ^ ((row & 7) << 4);
      gload_lds16((const char*)Ab + (((size_t)(m0 + row) * K + kt) << 1) + off,
                  (char*)lA + (j * 4 + w) * 1024);
      gload_lds16((const char*)BTb + (((size_t)(n0 + row) * K + kt) << 1) + off,
                  (char*)lB + (j * 4 + w) * 1024);
    }
    asm volatile("s_waitcnt vmcnt(0)" ::: "memory");
    __syncthreads();
#pragma unroll
    for (int s = 0; s < 2; ++s) {
      short8 af[4], bf[4];
#pragma unroll
      for (int mi = 0; mi < 4; ++mi) {
        int row = wm + mi * 16 + lr;
        af[mi] = *(const short8*)(lA + row * 64 + ((s * 32 + lk * 8) ^ ((row & 7) << 3)));
      }
#pragma unroll
      for (int ni = 0; ni < 4; ++ni) {
        int row = wn + ni * 16 + lr;
        bf[ni] = *(const short8*)(lB + row * 64 + ((s * 32 + lk * 8) ^ ((row & 7) << 3)));
      }
#pragma unroll
      for (int mi = 0; mi < 4; ++mi)
#pragma unroll
        for (int ni = 0; ni < 4; ++ni)
          acc[mi][ni] = __builtin_amdgcn_mfma_f32_16x16x32_bf16(af[mi], bf[ni], acc[mi][ni], 0, 0, 0);
    }
    __syncthreads();
  }

  if (MODE == 2) {
    float rs[4][4];
#pragma unroll
    for (int mi = 0; mi < 4; ++mi)
#pragma unroll
      for (int r = 0; r < 4; ++r) rs[mi][r] = 0.f;
#pragma unroll
    for (int mi = 0; mi < 4; ++mi)
#pragma unroll
      for (int ni = 0; ni < 4; ++ni) {
        int gn = n0 + wn + ni * 16 + lr;
        float mv = (mask[(size_t)z * N + gn] != 0) ? 1.0f : 0.0f;
#pragma unroll
        for (int r = 0; r < 4; ++r) {
          int gm = m0 + wm + mi * 16 + lk * 4 + r;
          float p = __expf(acc[mi][ni][r] - 1.0f) * mv;
          rs[mi][r] += p;
          ((unsigned short*)out)[(size_t)z * sOut + (size_t)gm * N + gn] = f2bf(p);
        }
      }
#pragma unroll
    for (int mi = 0; mi < 4; ++mi)
#pragma unroll
      for (int r = 0; r < 4; ++r) {
        float s = rs[mi][r];
        s += __shfl_xor(s, 1); s += __shfl_xor(s, 2); s += __shfl_xor(s, 4); s += __shfl_xor(s, 8);
        if (lr == 0) {
          int gm = m0 + wm + mi * 16 + lk * 4 + r;
          atomicAdd(&lbuf[(size_t)z * M + gm], s);
        }
      }
  } else if (MODE == 3) {
#pragma unroll
    for (int mi = 0; mi < 4; ++mi)
#pragma unroll
      for (int r = 0; r < 4; ++r) {
        int gm = m0 + wm + mi * 16 + lk * 4 + r;
        float rl = 1.0f / lbuf[(size_t)z * M + gm];
#pragma unroll
        for (int ni = 0; ni < 4; ++ni) {
          int gn = n0 + wn + ni * 16 + lr;
          ((unsigned short*)out)[(size_t)z * sOut + (size_t)gm * N + gn] = f2bf(acc[mi][ni][r] * rl);
        }
      }
  } else {
#pragma unroll
    for (int mi = 0; mi < 4; ++mi)
#pragma unroll
      for (int ni = 0; ni < 4; ++ni) {
        int gn = n0 + wn + ni * 16 + lr;
        float bs = bias[gn];
#pragma unroll
        for (int r = 0; r < 4; ++r) {
          int gm = m0 + wm + mi * 16 + lk * 4 + r;
          float v = acc[mi][ni][r] + bs;
          if (MODE == 0) v = fmaxf(v, 0.f);
          if (MODE == 0) ((unsigned short*)out)[(size_t)gm * N + gn] = f2bf(v);
          else           ((float*)out)[(size_t)gm * N + gn] = v;
        }
      }
  }
}

// ---------------- LN1: nattn = LN(O)*g+b (bf16), resid = nattn + text1 (f32) ----------------
__global__ __launch_bounds__(256) void k_ln1(const unsigned short* __restrict__ O,
                                             const float* __restrict__ text1,
                                             const float* __restrict__ g,
                                             const float* __restrict__ bvec,
                                             unsigned short* __restrict__ nattn,
                                             float* __restrict__ resid) {
  int row = blockIdx.x * 4 + (threadIdx.x >> 6);
  int l = threadIdx.x & 63;
  size_t base = (size_t)row * H_ + l * 8;
  short8 ov = *(const short8*)(O + base);
  float x[8];
#pragma unroll
  for (int i = 0; i < 8; ++i) x[i] = bf2f((unsigned short)ov[i]);
  float s = 0.f, q = 0.f;
#pragma unroll
  for (int i = 0; i < 8; ++i) { s += x[i]; q += x[i] * x[i]; }
#pragma unroll
  for (int m = 1; m < 64; m <<= 1) { s += __shfl_xor(s, m); q += __shfl_xor(q, m); }
  float mean = s * (1.f / 512.f);
  float var = q * (1.f / 512.f) - mean * mean;
  float rstd = rsqrtf(var + 1e-6f);
  f32x4 g0 = *(const f32x4*)(g + l * 8), g1v = *(const f32x4*)(g + l * 8 + 4);
  f32x4 b0 = *(const f32x4*)(bvec + l * 8), b1v = *(const f32x4*)(bvec + l * 8 + 4);
  f32x4 t0 = *(const f32x4*)(text1 + base), t1 = *(const f32x4*)(text1 + base + 4);
  short8 no;
  f32x4 r0, r1;
#pragma unroll
  for (int i = 0; i < 4; ++i) {
    float y0 = (x[i] - mean) * rstd * g0[i] + b0[i];
    float y1 = (x[4 + i] - mean) * rstd * g1v[i] + b1v[i];
    no[i] = (short)f2bf(y0); no[4 + i] = (short)f2bf(y1);
    r0[i] = y0 + t0[i]; r1[i] = y1 + t1[i];
  }
  *(short8*)(nattn + base) = no;
  *(f32x4*)(resid + base) = r0;
  *(f32x4*)(resid + base + 4) = r1;
}

// ---------------- LN2(ff) + resid -> out ----------------
__global__ __launch_bounds__(256) void k_ln2(const float* __restrict__ ff,
                                             const float* __restrict__ resid,
                                             const float* __restrict__ g2,
                                             const float* __restrict__ bb2,
                                             float* __restrict__ out) {
  int row = blockIdx.x * 4 + (threadIdx.x >> 6);
  int l = threadIdx.x & 63;
  size_t base = (size_t)row * H_ + l * 8;
  f32x4 x0 = *(const f32x4*)(ff + base);
  f32x4 x1 = *(const f32x4*)(ff + base + 4);
  float s = x0[0] + x0[1] + x0[2] + x0[3] + x1[0] + x1[1] + x1[2] + x1[3];
  float q = x0[0]*x0[0] + x0[1]*x0[1] + x0[2]*x0[2] + x0[3]*x0[3]
          + x1[0]*x1[0] + x1[1]*x1[1] + x1[2]*x1[2] + x1[3]*x1[3];
#pragma unroll
  for (int m = 1; m < 64; m <<= 1) { s += __shfl_xor(s, m); q += __shfl_xor(q, m); }
  float mean = s * (1.f / 512.f);
  float var = q * (1.f / 512.f) - mean * mean;
  float rstd = rsqrtf(var + 1e-6f);
  f32x4 g0 = *(const f32x4*)(g2 + l * 8), g1v = *(const f32x4*)(g2 + l * 8 + 4);
  f32x4 b0 = *(const f32x4*)(bb2 + l * 8), b1v = *(const f32x4*)(bb2 + l * 8 + 4);
  f32x4 r0 = *(const f32x4*)(resid + base), r1 = *(const f32x4*)(resid + base + 4);
  f32x4 o0, o1;
#pragma unroll
  for (int i = 0; i < 4; ++i) {
    o0[i] = (x0[i] - mean) * rstd * g0[i] + b0[i] + r0[i];
    o1[i] = (x1[i] - mean) * rstd * g1v[i] + b1v[i] + r1[i];
  }
  *(f32x4*)(out + base) = o0;
  *(f32x4*)(out + base + 4) = o1;
}

extern "C" void kernel_launch(void* const* d_in, const int* in_sizes, int n_in,
                              void* d_out, int out_size, void* d_ws, size_t ws_size,
                              hipStream_t stream) {
  const float* text1 = (const float*)d_in[0];
  const float* text2 = (const float*)d_in[1];
  // d_in[2] = text1_mask (unused by reference output)
  const int* mask2 = (const int*)d_in[3];
  const float* W1 = (const float*)d_in[4];
  const float* b1 = (const float*)d_in[5];
  const float* W2 = (const float*)d_in[6];
  const float* b2 = (const float*)d_in[7];
  const float* g1 = (const float*)d_in[8];
  const float* bb1 = (const float*)d_in[9];
  const float* g2 = (const float*)d_in[10];
  const float* bb2 = (const float*)d_in[11];

  const size_t MiB = 1024ull * 1024ull;
  char* ws = (char*)d_ws;
  unsigned short* W1T   = (unsigned short*)(ws + 0 * MiB);    // 1 MiB
  unsigned short* W2T   = (unsigned short*)(ws + 1 * MiB);    // 1 MiB
  float*          lbuf  = (float*)(ws + 2 * MiB);             // 128 KiB
  unsigned short* qn    = (unsigned short*)(ws + 4 * MiB);    // 32 MiB [4,36)
  unsigned short* kn    = (unsigned short*)(ws + 36 * MiB);   // 32 MiB [36,68)
  unsigned short* vt    = (unsigned short*)(ws + 68 * MiB);   // 32 MiB [68,100)
  unsigned short* P     = (unsigned short*)(ws + 100 * MiB);  // 64 MiB [100,164) (8-batch chunk)
  unsigned short* O     = (unsigned short*)(ws + 164 * MiB);  // 32 MiB [164,196)
  // aliases (phase-ordered, see lifetimes):
  unsigned short* nattn = (unsigned short*)(ws + 100 * MiB);  // 32 MiB over P (P dead after pass2)
  float*          resid = (float*)(ws + 4 * MiB);             // 64 MiB over qn+kn (dead after pass1)
  unsigned short* hbuf  = (unsigned short*)(ws + 132 * MiB);  // 64 MiB over P-rest + O (dead after LN1)
  float*          ff    = (float*)(ws + 68 * MiB);            // 64 MiB over vt + nattn (dead after FF1)
  float* outp = (float*)d_out;

  hipMemsetAsync(lbuf, 0, (size_t)B_ * S1_ * sizeof(float), stream);

  k_rownorm<<<dim3(B_ * S1_ / 4), 256, 0, stream>>>(text1, qn);
  k_rownorm<<<dim3(B_ * S2_ / 4), 256, 0, stream>>>(text2, kn);
  k_tw<<<dim3(512 * 1024 / 256), 256, 0, stream>>>(W1, W1T, 9, 1024);
  k_tw<<<dim3(512 * 1024 / 256), 256, 0, stream>>>(W2, W2T, 10, 512);
  k_tvt<<<dim3(H_ / 64, S2_ / 64, B_), 256, 0, stream>>>(text2, vt);

  for (int c = 0; c < 2; ++c) {
    const int c0 = c * 8;
    // pass1: P = exp(qn @ kn^T - 1) * mask, row sums -> lbuf
    k_gemm<2><<<dim3(S2_ / 128, S1_ / 128, 8), 256, 0, stream>>>(
        qn + (size_t)c0 * S1_ * H_, kn + (size_t)c0 * S2_ * H_,
        nullptr, mask2 + (size_t)c0 * S2_, lbuf + (size_t)c0 * S1_, P,
        S1_, S2_, H_, (long)S1_ * H_, (long)S2_ * H_, (long)S1_ * S2_);
    // pass2: O = (P @ V) / l   (bf16)
    k_gemm<3><<<dim3(H_ / 128, S1_ / 128, 8), 256, 0, stream>>>(
        P, vt + (size_t)c0 * H_ * S2_,
        nullptr, nullptr, lbuf + (size_t)c0 * S1_, O + (size_t)c0 * S1_ * H_,
        S1_, H_, S2_, (long)S1_ * S2_, (long)H_ * S2_, (long)S1_ * H_);
  }

  k_ln1<<<dim3(B_ * S1_ / 4), 256, 0, stream>>>(O, text1, g1, bb1, nattn, resid);
  k_gemm<0><<<dim3(1024 / 128, 32768 / 128, 1), 256, 0, stream>>>(
      nattn, W1T, b1, nullptr, nullptr, hbuf, 32768, 1024, 512, 0, 0, 0);
  k_gemm<1><<<dim3(512 / 128, 32768 / 128, 1), 256, 0, stream>>>(
      hbuf, W2T, b2, nullptr, nullptr, ff, 32768, 512, 1024, 0, 0, 0);
  k_ln2<<<dim3(32768 / 4), 256, 0, stream>>>(ff, resid, g2, bb2, outp);
}